// Round 2
// baseline (51.856 us; speedup 1.0000x reference)
//
#include <hip/hip_runtime.h>

#define DS   256    // downsampled dim (2048/8)
#define FULL 2048
#define NIMG 8

// Fast segment-mean contribution along a 256-long line, 256 threads.
// Cumsum: shfl_up wave scan + cross-wave combine. prev/nxt: ballot bit-ops.
// Returns lr+rl (or 2x where invalid), matching the reference _seg_means.
__device__ __forceinline__ float seg_fast(float x, bool z, int j,
                                          float* s_cs,
                                          unsigned long long* s_msk,
                                          float* s_ws) {
    const int lane = j & 63;
    const int w    = j >> 6;
    unsigned long long m = __ballot(z);

    // wave-level inclusive cumsum in registers
    float s = x;
    #pragma unroll
    for (int off = 1; off < 64; off <<= 1) {
        float t = __shfl_up(s, off, 64);
        if (lane >= off) s += t;
    }
    if (lane == 63) s_ws[w]  = s;
    if (lane == 0)  s_msk[w] = m;
    __syncthreads();

    // cross-wave prefix
    float pre = 0.f;
    for (int ww = 0; ww < w; ++ww) pre += s_ws[ww];
    s += pre;
    s_cs[j] = s;

    // prev = last boundary index < j; nxt = first boundary index > j
    unsigned long long lo = m & ((1ULL << lane) - 1ULL);
    int prev = -1;
    if (lo) prev = (w << 6) + 63 - __builtin_clzll(lo);
    else {
        for (int ww = w - 1; ww >= 0; --ww) {
            unsigned long long mm = s_msk[ww];
            if (mm) { prev = (ww << 6) + 63 - __builtin_clzll(mm); break; }
        }
    }
    unsigned long long hi = m & ~((2ULL << lane) - 1ULL);
    int nxt = DS;
    if (hi) nxt = (w << 6) + __builtin_ctzll(hi);
    else {
        for (int ww = w + 1; ww < 4; ++ww) {
            unsigned long long mm = s_msk[ww];
            if (mm) { nxt = (ww << 6) + __builtin_ctzll(mm); break; }
        }
    }
    __syncthreads();   // s_cs fully written

    bool valid = (!z) && (prev >= 0) && (nxt < DS);
    if (valid) {
        float cs_j   = s_cs[j];
        float cs_pm1 = (prev > 0) ? s_cs[prev - 1] : 0.f;
        float cs_n   = s_cs[nxt];
        float cs_jm1 = (j > 0) ? s_cs[j - 1] : 0.f;
        return (cs_j - cs_pm1) / (float)(j - prev + 1)
             + (cs_n - cs_jm1) / (float)(nxt - j + 1);
    }
    return 2.f * x;
}

// K1: gather downsampled values + horizontal segment means.
__global__ __launch_bounds__(256) void k_horiz(const float* __restrict__ x0,
                                               const int* __restrict__ x1,
                                               float2* __restrict__ xz,
                                               float* __restrict__ yH) {
    __shared__ float s_cs[DS];
    __shared__ unsigned long long s_msk[4];
    __shared__ float s_ws[4];
    int n = blockIdx.x >> 8;
    int i = blockIdx.x & 255;
    int j = threadIdx.x;
    size_t src = (((size_t)n * FULL) + (size_t)i * 8) * FULL + (size_t)j * 8;
    float x = x0[src];
    bool  z = (x1[src] == 0);
    int d = (n << 16) + (i << 8) + j;
    xz[d] = make_float2(x, z ? 1.f : 0.f);
    yH[d] = seg_fast(x, z, j, s_cs, s_msk, s_ws);
}

// K2: vertical segment means on compact array, accumulate in place.
__global__ __launch_bounds__(256) void k_vert(const float2* __restrict__ xz,
                                              float* __restrict__ yH) {
    __shared__ float s_cs[DS];
    __shared__ unsigned long long s_msk[4];
    __shared__ float s_ws[4];
    int n = blockIdx.x >> 8;
    int c = blockIdx.x & 255;
    int t = threadIdx.x;
    int d = (n << 16) + (t << 8) + c;
    float2 v = xz[d];
    float r = seg_fast(v.x, v.y != 0.f, t, s_cs, s_msk, s_ws);
    yH[d] += r;
}

// K3: nearest-neighbor 8x8 upsample, 32 B per thread coalesced stores.
__global__ __launch_bounds__(256) void k_up(const float* __restrict__ yD,
                                            float4* __restrict__ out) {
    int gid = blockIdx.x * 256 + threadIdx.x;
    int g2  = gid << 1;          // first of two float4 slots (32 B)
    int j4  = g2 & 511;          // float4 index within a 2048-wide row
    int r   = g2 >> 9;           // n*2048 + I (output row)
    int I   = r & 2047;
    int n   = r >> 11;
    int jd  = j4 >> 1;           // downsampled column (same for both slots)
    float v = yD[(n << 16) + ((I >> 3) << 8) + jd];
    float4 vv = make_float4(v, v, v, v);
    out[g2]     = vv;
    out[g2 + 1] = vv;
}

extern "C" void kernel_launch(void* const* d_in, const int* in_sizes, int n_in,
                              void* d_out, int out_size, void* d_ws, size_t ws_size,
                              hipStream_t stream) {
    const float* x0 = (const float*)d_in[0];
    const int*   x1 = (const int*)d_in[1];
    float* out = (float*)d_out;

    // workspace layout: xz (4MB float2) | yH (2MB float)
    float2* xz = (float2*)d_ws;
    float*  yH = (float*)(xz + NIMG * DS * DS);

    dim3 blk(256);
    k_horiz<<<dim3(NIMG * DS), blk, 0, stream>>>(x0, x1, xz, yH);
    k_vert <<<dim3(NIMG * DS), blk, 0, stream>>>(xz, yH);
    // 8 imgs * 2048 rows * 512 float4 per row / 2 per thread = 4194304 threads
    k_up   <<<dim3(16384), blk, 0, stream>>>(yH, (float4*)out);
}